// Round 1
// baseline (86.177 us; speedup 1.0000x reference)
//
#include <hip/hip_runtime.h>
#include <math.h>

#define BLK 256

// tanh(x) = (e^{2x}-1)/(e^{2x}+1); clamp so __expf never overflows.
// |err| ~ 1e-6 absolute — far inside any sane validation threshold.
__device__ __forceinline__ float fast_tanh(float x) {
    x = fminf(9.0f, fmaxf(-9.0f, x));
    float e = __expf(2.0f * x);
    return __fdividef(e - 1.0f, e + 1.0f);
}

__global__ __launch_bounds__(BLK) void fk_fused_kernel(
    const float* __restrict__ joints,    // [B,7]
    const float* __restrict__ fk_params, // [7,4] : alpha, a, d, offset
    const float* __restrict__ W1, const float* __restrict__ b1,  // [15,7],[15]
    const float* __restrict__ W2, const float* __restrict__ b2,  // [15,15],[15]
    const float* __restrict__ W3, const float* __restrict__ b3,  // [7,15],[7]
    float* __restrict__ out,             // [B,3]
    int B)
{
    __shared__ float sW1[105], sb1[15], sW2[225], sb2[15], sW3[105], sb3[7];
    __shared__ float s_ca[7], s_sa[7], s_a[7], s_d[7], s_off[7];
    __shared__ float sJ[BLK * 7];   // reused for output staging (BLK*3 <= BLK*7)

    const int t = threadIdx.x;

    // ---- stage weights into LDS (broadcast reads later are conflict-free) ----
    for (int i = t; i < 105; i += BLK) sW1[i] = W1[i];
    for (int i = t; i < 225; i += BLK) sW2[i] = W2[i];
    for (int i = t; i < 105; i += BLK) sW3[i] = W3[i];
    if (t < 15) { sb1[t] = b1[t]; sb2[t] = b2[t]; }
    if (t < 7)  {
        sb3[t]  = b3[t];
        float alpha = fk_params[t * 4 + 0];
        s_a[t]   = fk_params[t * 4 + 1];
        s_d[t]   = fk_params[t * 4 + 2];
        s_off[t] = fk_params[t * 4 + 3];
        s_ca[t] = cosf(alpha);
        s_sa[t] = sinf(alpha);
    }

    // ---- stage this block's joints, coalesced ----
    const int base = blockIdx.x * BLK;          // first sample of this block
    const int nval = min(BLK * 7, B * 7 - base * 7);
    for (int i = t; i < nval; i += BLK) sJ[i] = joints[base * 7 + i];
    __syncthreads();

    const int sample = base + t;
    float r0[4], r1[4], r2[4];   // rows 0..2 of ee (row 3 stays [0,0,0,1])

    if (sample < B) {
        float j[7];
        #pragma unroll
        for (int k = 0; k < 7; ++k) j[k] = sJ[t * 7 + k];

        // ---- layer 1: 7 -> 15, tanh ----
        float h1[15];
        #pragma unroll
        for (int i = 0; i < 15; ++i) {
            float s = sb1[i];
            #pragma unroll
            for (int k = 0; k < 7; ++k) s = fmaf(j[k], sW1[i * 7 + k], s);
            h1[i] = fast_tanh(s);
        }
        // ---- layer 2: 15 -> 15, tanh ----
        float h2[15];
        #pragma unroll
        for (int i = 0; i < 15; ++i) {
            float s = sb2[i];
            #pragma unroll
            for (int k = 0; k < 15; ++k) s = fmaf(h1[k], sW2[i * 15 + k], s);
            h2[i] = fast_tanh(s);
        }

        // ---- layer 3 (7 outputs) fused with DH chain ----
        #pragma unroll
        for (int jj = 0; jj < 7; ++jj) {
            float s = sb3[jj];
            #pragma unroll
            for (int k = 0; k < 15; ++k) s = fmaf(h2[k], sW3[jj * 15 + k], s);
            float corr = fast_tanh(s);
            float th = j[jj] + corr + s_off[jj];
            float st, ct;
            sincosf(th, &st, &ct);
            const float ca = s_ca[jj], sa = s_sa[jj], a = s_a[jj], d = s_d[jj];
            // M rows: m0=[ct,-st,0,a]  m1=[st*ca,ct*ca,-sa,-d*sa]  m2=[st*sa,ct*sa,ca,ca*d]
            const float m10 = st * ca, m11 = ct * ca, m12 = -sa, m13 = -d * sa;
            const float m20 = st * sa, m21 = ct * sa, m22 = ca,  m23 = ca * d;
            if (jj == 0) {
                r0[0] = ct;  r0[1] = -st; r0[2] = 0.0f; r0[3] = a;
                r1[0] = m10; r1[1] = m11; r1[2] = m12;  r1[3] = m13;
                r2[0] = m20; r2[1] = m21; r2[2] = m22;  r2[3] = m23;
            } else {
                // ee_new[i][k] = sum_l ee[i][l] * M[l][k], M row3 = e3
                float n0, n1, n2, n3;
                n0 = r0[0]*ct + r0[1]*m10 + r0[2]*m20;
                n1 = -r0[0]*st + r0[1]*m11 + r0[2]*m21;
                n2 =             r0[1]*m12 + r0[2]*m22;
                n3 = r0[0]*a  + r0[1]*m13 + r0[2]*m23 + r0[3];
                r0[0]=n0; r0[1]=n1; r0[2]=n2; r0[3]=n3;
                n0 = r1[0]*ct + r1[1]*m10 + r1[2]*m20;
                n1 = -r1[0]*st + r1[1]*m11 + r1[2]*m21;
                n2 =             r1[1]*m12 + r1[2]*m22;
                n3 = r1[0]*a  + r1[1]*m13 + r1[2]*m23 + r1[3];
                r1[0]=n0; r1[1]=n1; r1[2]=n2; r1[3]=n3;
                n0 = r2[0]*ct + r2[1]*m10 + r2[2]*m20;
                n1 = -r2[0]*st + r2[1]*m11 + r2[2]*m21;
                n2 =             r2[1]*m12 + r2[2]*m22;
                n3 = r2[0]*a  + r2[1]*m13 + r2[2]*m23 + r2[3];
                r2[0]=n0; r2[1]=n1; r2[2]=n2; r2[3]=n3;
            }
        }
    }

    // ---- stage outputs through LDS, write coalesced ----
    __syncthreads();           // done reading sJ as joints
    if (sample < B) {
        sJ[t * 3 + 0] = r0[3];
        sJ[t * 3 + 1] = r1[3];
        sJ[t * 3 + 2] = r2[3];
    }
    __syncthreads();
    const int onval = min(BLK * 3, B * 3 - base * 3);
    for (int i = t; i < onval; i += BLK) out[base * 3 + i] = sJ[i];
}

extern "C" void kernel_launch(void* const* d_in, const int* in_sizes, int n_in,
                              void* d_out, int out_size, void* d_ws, size_t ws_size,
                              hipStream_t stream) {
    const float* joints    = (const float*)d_in[0];
    const float* fk_params = (const float*)d_in[1];
    const float* W1 = (const float*)d_in[2];
    const float* b1 = (const float*)d_in[3];
    const float* W2 = (const float*)d_in[4];
    const float* b2 = (const float*)d_in[5];
    const float* W3 = (const float*)d_in[6];
    const float* b3 = (const float*)d_in[7];
    float* out = (float*)d_out;

    const int B = in_sizes[0] / 7;
    const int nblk = (B + BLK - 1) / BLK;
    fk_fused_kernel<<<nblk, BLK, 0, stream>>>(joints, fk_params, W1, b1, W2, b2,
                                              W3, b3, out, B);
}

// Round 2
// 83.656 us; speedup vs baseline: 1.0301x; 1.0301x over previous
//
#include <hip/hip_runtime.h>
#include <math.h>

#define BLK 256

// tanh(x) = 1 - 2/(e^{2x}+1); clamp so __expf never overflows.
__device__ __forceinline__ float fast_tanh(float x) {
    x = fminf(9.0f, fmaxf(-9.0f, x));
    float e = __expf(2.0f * x);                 // v_exp_f32 after log2e fold
    return fmaf(-2.0f, __frcp_rn(e + 1.0f), 1.0f);
}

// sin/cos via hardware v_sin_f32 / v_cos_f32 (operate on revolutions).
__device__ __forceinline__ void fast_sincos(float x, float& s, float& c) {
    const float INV2PI = 0.15915494309189535f;
    float r = x * INV2PI;
    r = r - floorf(r);                          // reduce to [0,1)
    s = __builtin_amdgcn_sinf(r);
    c = __builtin_amdgcn_cosf(r);
}

__global__ __launch_bounds__(BLK) void fk_fused_kernel(
    const float* __restrict__ joints,    // [B,7]
    const float* __restrict__ fk_params, // [7,4] : alpha, a, d, offset
    const float* __restrict__ W1, const float* __restrict__ b1,  // [15,7],[15]
    const float* __restrict__ W2, const float* __restrict__ b2,  // [15,15],[15]
    const float* __restrict__ W3, const float* __restrict__ b3,  // [7,15],[7]
    float* __restrict__ out,             // [B,3]
    int B)
{
    __shared__ float sJ[BLK * 7];   // joints staging, reused for output staging

    const int t = threadIdx.x;
    const int base = blockIdx.x * BLK;

    // ---- stage this block's joints, coalesced ----
    const int nval = min(BLK * 7, B * 7 - base * 7);
    for (int i = t; i < nval; i += BLK) sJ[i] = joints[base * 7 + i];
    __syncthreads();

    const int sample = base + t;
    float r0[4], r1[4], r2[4];   // rows 0..2 of ee (row 3 stays [0,0,0,1])

    if (sample < B) {
        float j[7];
        #pragma unroll
        for (int k = 0; k < 7; ++k) j[k] = sJ[t * 7 + k];

        // ---- layer 1: 7 -> 15, tanh.  Weights are wave-uniform: compiler
        // emits scalar loads (s_load) for W*/b* — VALU reads SGPR directly. ----
        float h1[15];
        #pragma unroll
        for (int i = 0; i < 15; ++i) {
            float s = b1[i];
            #pragma unroll
            for (int k = 0; k < 7; ++k) s = fmaf(j[k], W1[i * 7 + k], s);
            h1[i] = fast_tanh(s);
        }
        // ---- layer 2: 15 -> 15, tanh ----
        float h2[15];
        #pragma unroll
        for (int i = 0; i < 15; ++i) {
            float s = b2[i];
            #pragma unroll
            for (int k = 0; k < 15; ++k) s = fmaf(h1[k], W2[i * 15 + k], s);
            h2[i] = fast_tanh(s);
        }

        // ---- layer 3 (7 outputs) fused with DH chain ----
        #pragma unroll
        for (int jj = 0; jj < 7; ++jj) {
            float s = b3[jj];
            #pragma unroll
            for (int k = 0; k < 15; ++k) s = fmaf(h2[k], W3[jj * 15 + k], s);
            float corr = fast_tanh(s);

            const float alpha = fk_params[jj * 4 + 0];
            const float a     = fk_params[jj * 4 + 1];
            const float d     = fk_params[jj * 4 + 2];
            const float off   = fk_params[jj * 4 + 3];

            float th = j[jj] + corr + off;
            float st, ct, sa, ca;
            fast_sincos(th, st, ct);
            fast_sincos(alpha, sa, ca);

            // M rows: m0=[ct,-st,0,a]  m1=[st*ca,ct*ca,-sa,-d*sa]  m2=[st*sa,ct*sa,ca,ca*d]
            const float m10 = st * ca, m11 = ct * ca, m12 = -sa, m13 = -d * sa;
            const float m20 = st * sa, m21 = ct * sa, m22 = ca,  m23 = ca * d;
            if (jj == 0) {
                r0[0] = ct;  r0[1] = -st; r0[2] = 0.0f; r0[3] = a;
                r1[0] = m10; r1[1] = m11; r1[2] = m12;  r1[3] = m13;
                r2[0] = m20; r2[1] = m21; r2[2] = m22;  r2[3] = m23;
            } else {
                // ee_new[i][k] = sum_l ee[i][l] * M[l][k], M row3 = e3
                float n0, n1, n2, n3;
                n0 = r0[0]*ct + r0[1]*m10 + r0[2]*m20;
                n1 = -r0[0]*st + r0[1]*m11 + r0[2]*m21;
                n2 =             r0[1]*m12 + r0[2]*m22;
                n3 = r0[0]*a  + r0[1]*m13 + r0[2]*m23 + r0[3];
                r0[0]=n0; r0[1]=n1; r0[2]=n2; r0[3]=n3;
                n0 = r1[0]*ct + r1[1]*m10 + r1[2]*m20;
                n1 = -r1[0]*st + r1[1]*m11 + r1[2]*m21;
                n2 =             r1[1]*m12 + r1[2]*m22;
                n3 = r1[0]*a  + r1[1]*m13 + r1[2]*m23 + r1[3];
                r1[0]=n0; r1[1]=n1; r1[2]=n2; r1[3]=n3;
                n0 = r2[0]*ct + r2[1]*m10 + r2[2]*m20;
                n1 = -r2[0]*st + r2[1]*m11 + r2[2]*m21;
                n2 =             r2[1]*m12 + r2[2]*m22;
                n3 = r2[0]*a  + r2[1]*m13 + r2[2]*m23 + r2[3];
                r2[0]=n0; r2[1]=n1; r2[2]=n2; r2[3]=n3;
            }
        }
    }

    // ---- stage outputs through LDS, write coalesced ----
    __syncthreads();           // done reading sJ as joints
    if (sample < B) {
        sJ[t * 3 + 0] = r0[3];
        sJ[t * 3 + 1] = r1[3];
        sJ[t * 3 + 2] = r2[3];
    }
    __syncthreads();
    const int onval = min(BLK * 3, B * 3 - base * 3);
    for (int i = t; i < onval; i += BLK) out[base * 3 + i] = sJ[i];
}

extern "C" void kernel_launch(void* const* d_in, const int* in_sizes, int n_in,
                              void* d_out, int out_size, void* d_ws, size_t ws_size,
                              hipStream_t stream) {
    const float* joints    = (const float*)d_in[0];
    const float* fk_params = (const float*)d_in[1];
    const float* W1 = (const float*)d_in[2];
    const float* b1 = (const float*)d_in[3];
    const float* W2 = (const float*)d_in[4];
    const float* b2 = (const float*)d_in[5];
    const float* W3 = (const float*)d_in[6];
    const float* b3 = (const float*)d_in[7];
    float* out = (float*)d_out;

    const int B = in_sizes[0] / 7;
    const int nblk = (B + BLK - 1) / BLK;
    fk_fused_kernel<<<nblk, BLK, 0, stream>>>(joints, fk_params, W1, b1, W2, b2,
                                              W3, b3, out, B);
}